// Round 16
// baseline (10331.061 us; speedup 1.0000x reference)
//
#include <hip/hip_runtime.h>

// ---------------------------------------------------------------------------
// RAE forward, single-product f16 MFMA GEMMs + deterministic split-K.
// Weights AND activations f16 (R15; absmax stayed at bf16-compare floor).
// GEMM core (proven R12-R15): contiguous-line staging via global_load_lds,
// sigma(r)=(r>>1)&3 k-part swizzle (pre-swizzled global src, linear LDS,
// swizzled read), 3-buffer LDS, counted s_waitcnt vmcnt + raw s_barrier
// 2-deep pipeline, bijective XCD swizzle, split-K into P[kz][M][N] f32
// summed in the LN pass.
// NEW (R16): wide 128x256 tile (gemm_w2) — one block computes two adjacent
// N-tiles, staging A ONCE (24KB/step for 2x area = 0.75x bytes/area, ~25%
// total staging-traffic cut). 4 waves, 72KB LDS -> 2 blocks/CU preserved
// (R9's 1-block/CU failure mode avoided); 6 loads/stage -> same vmcnt(6)
// cadence; per-output k-order unchanged -> bit-identical numerics.
// Narrow 128x128 (gemm_s1) kept for N=640.
//
// FAILED-EXPERIMENT LEDGER (do not repeat):
//  - A streamed global->VGPR (R5: -27%, R7: -330%)
//  - split-K target 512 / cap 16 (R8: +4% slower) — keep 448 / cap 8
//  - 8-wave 512-thread 96KB 128x256 tile (R9: +12% slower, 1 block/CU)
//  - counted-vmcnt alone (R12: +2%); bank-swizzle fix alone (R14: +1.8%)
// ---------------------------------------------------------------------------

typedef _Float16 f16;
typedef _Float16 half8 __attribute__((ext_vector_type(8)));
typedef float floatx4 __attribute__((ext_vector_type(4)));

__device__ __forceinline__ void gld_lds16(const f16* g, f16* l) {
    __builtin_amdgcn_global_load_lds(
        (const __attribute__((address_space(1))) void*)g,
        (__attribute__((address_space(3))) void*)l, 16, 0, 0);
}

// --------------------- GEMM, narrow 128x128 (N % 256 != 0) ------------------
// MODE 0: plain A. MODE 1: enc-cat. MODE 2: dec-cat.
// OUT 1: bias+relu+f16; OUT 2: bias+fp32; OUT 3: f32 partial slice.
template<int MODE, int OUT>
__global__ __launch_bounds__(256, 2) void gemm_s1(
    const f16* __restrict__ Ahi, int lda,
    const f16* __restrict__ Whi,
    const float* __restrict__ bias,
    f16* __restrict__ Chi, float* __restrict__ Cf,
    float* __restrict__ Pf, int ksplit,
    int M, int N, int K, int Kpad, int kbound, int Lo, int Li,
    const f16* __restrict__ tsrow,
    int gy, int q, int r)
{
    __shared__ __align__(16) f16 sm[3][2][128][32];   // 48 KiB

    const int lane = threadIdx.x & 63;
    const int wid  = threadIdx.x >> 6;

    const int bid = blockIdx.x;
    const int xcd = bid & 7, jj = bid >> 3;
    const int rank = (xcd < r) ? xcd * (q + 1) + jj
                               : r * (q + 1) + (xcd - r) * q + jj;
    const int t  = rank / ksplit;
    const int kz = rank - t * ksplit;
    const int bx = t / gy, by = t - bx * gy;
    const int bm = by * 128;
    const int bn = bx * 128;

    const int rl   = lane >> 2;
    const int kp   = lane & 3;
    const int kofs = ((kp ^ ((rl >> 1) & 3)) << 3);

    const f16* aph[2];
    const f16* wph[2];
    #pragma unroll
    for (int it = 0; it < 2; it++) {
        const int trow = wid * 32 + it * 16 + rl;
        int gr = bm + trow; if (gr > M - 1) gr = M - 1;
        int arow;
        if (MODE == 1) { int b = gr / Lo; int l = gr - b * Lo; arow = b * Li + l; }
        else arow = gr;
        aph[it] = Ahi + (size_t)arow * lda;
        const int col = bn + trow;
        wph[it] = Whi + (size_t)col * K;
    }

    auto stage = [&](int buf, int sstep) {   // exactly 4 loads/wave
        const int k0 = sstep << 5;
        #pragma unroll
        for (int it = 0; it < 2; it++) {
            const int lbase = wid * 32 + it * 16;
            const f16* sh;
            if (MODE == 0 || k0 < kbound) sh = aph[it] + (k0 + kofs);
            else                          sh = tsrow + (k0 - kbound) + kofs;
            gld_lds16(sh, &sm[buf][0][lbase][0] + (size_t)lane * 8);
            int kw = k0 + kofs; if (kw > K - 8) kw = K - 8;
            gld_lds16(wph[it] + kw, &sm[buf][1][lbase][0] + (size_t)lane * 8);
        }
    };

    floatx4 acc1[4][4] = {};

    const int nst = Kpad >> 5;
    const int sps = (nst + ksplit - 1) / ksplit;
    const int s0  = kz * sps;
    int s1 = s0 + sps; if (s1 > nst) s1 = nst;

    const int kc  = lane >> 4;
    const int fr  = lane & 15;
    const int wr  = (wid >> 1) * 64;
    const int wc  = (wid & 1) * 64;
    const int ksw = ((kc ^ ((fr >> 1) & 3)) << 3);

    if (s0 < s1) {
        const int n = s1 - s0;
        stage(0, s0);
        stage(1, s0 + ((n > 1) ? 1 : 0));
        for (int j = 0; j < n; j++) {
            asm volatile("s_waitcnt vmcnt(4)" ::: "memory");
            asm volatile("s_barrier" ::: "memory");
            {
                int jt = j + 2; if (jt > n - 1) jt = n - 1;
                stage((j + 2) % 3, s0 + jt);
            }
            const int buf = j % 3;
            half8 ah[4], wh[4];
            #pragma unroll
            for (int m = 0; m < 4; m++)
                ah[m] = *(const half8*)&sm[buf][0][wr + m * 16 + fr][ksw];
            #pragma unroll
            for (int nn = 0; nn < 4; nn++)
                wh[nn] = *(const half8*)&sm[buf][1][wc + nn * 16 + fr][ksw];
            #pragma unroll
            for (int m = 0; m < 4; m++)
                #pragma unroll
                for (int nn = 0; nn < 4; nn++)
                    acc1[m][nn] = __builtin_amdgcn_mfma_f32_16x16x32_f16(ah[m], wh[nn], acc1[m][nn], 0, 0, 0);
        }
        asm volatile("s_waitcnt vmcnt(0)" ::: "memory");
    }

    const int q4 = (lane >> 4) * 4;
    const size_t MN = (size_t)M * N;
    #pragma unroll
    for (int nn = 0; nn < 4; nn++) {
        const int gcol = bn + wc + nn * 16 + fr;
        const float bv = (OUT == 3) ? 0.0f : bias[gcol];
        #pragma unroll
        for (int m = 0; m < 4; m++) {
            #pragma unroll
            for (int j = 0; j < 4; j++) {
                const int grow = bm + wr + m * 16 + q4 + j;
                if (grow < M) {
                    float v = acc1[m][nn][j] + bv;
                    const size_t o = (size_t)grow * N + gcol;
                    if (OUT == 3)      Pf[(size_t)kz * MN + o] = v;
                    else if (OUT == 2) Cf[o] = v;
                    else               Chi[o] = (f16)fmaxf(v, 0.0f);
                }
            }
        }
    }
}

// --------------------- GEMM, wide 128x256 (N % 256 == 0) --------------------
// Same pipeline; A staged once per block for 256 output cols. Each wave owns
// 64 rows x 128 cols (acc[4][8]); 6 loads/wave/stage -> vmcnt(6).
template<int MODE, int OUT>
__global__ __launch_bounds__(256, 2) void gemm_w2(
    const f16* __restrict__ Ahi, int lda,
    const f16* __restrict__ Whi,
    const float* __restrict__ bias,
    f16* __restrict__ Chi, float* __restrict__ Cf,
    float* __restrict__ Pf, int ksplit,
    int M, int N, int K, int Kpad, int kbound, int Lo, int Li,
    const f16* __restrict__ tsrow,
    int gy, int q, int r)
{
    __shared__ __align__(16) f16 smA[3][128][32];     // 24 KiB
    __shared__ __align__(16) f16 smW[3][256][32];     // 48 KiB

    const int lane = threadIdx.x & 63;
    const int wid  = threadIdx.x >> 6;

    const int bid = blockIdx.x;
    const int xcd = bid & 7, jj = bid >> 3;
    const int rank = (xcd < r) ? xcd * (q + 1) + jj
                               : r * (q + 1) + (xcd - r) * q + jj;
    const int t  = rank / ksplit;
    const int kz = rank - t * ksplit;
    const int bx = t / gy, by = t - bx * gy;
    const int bm = by * 128;
    const int bn = bx * 256;

    const int rl   = lane >> 2;
    const int kp   = lane & 3;
    const int kofs = ((kp ^ ((rl >> 1) & 3)) << 3);

    const f16* aph[2];
    const f16* wph[4];
    #pragma unroll
    for (int it = 0; it < 2; it++) {
        const int trow = wid * 32 + it * 16 + rl;
        int gr = bm + trow; if (gr > M - 1) gr = M - 1;
        int arow;
        if (MODE == 1) { int b = gr / Lo; int l = gr - b * Lo; arow = b * Li + l; }
        else arow = gr;
        aph[it] = Ahi + (size_t)arow * lda;
    }
    #pragma unroll
    for (int it = 0; it < 4; it++) {
        const int col = bn + wid * 64 + it * 16 + rl;   // N % 256 == 0 -> in range
        wph[it] = Whi + (size_t)col * K;
    }

    auto stage = [&](int buf, int sstep) {   // exactly 6 loads/wave
        const int k0 = sstep << 5;
        #pragma unroll
        for (int it = 0; it < 2; it++) {
            const f16* sh;
            if (MODE == 0 || k0 < kbound) sh = aph[it] + (k0 + kofs);
            else                          sh = tsrow + (k0 - kbound) + kofs;
            gld_lds16(sh, &smA[buf][wid * 32 + it * 16][0] + (size_t)lane * 8);
        }
        #pragma unroll
        for (int it = 0; it < 4; it++) {
            int kw = k0 + kofs; if (kw > K - 8) kw = K - 8;
            gld_lds16(wph[it] + kw, &smW[buf][wid * 64 + it * 16][0] + (size_t)lane * 8);
        }
    };

    floatx4 acc1[4][8] = {};

    const int nst = Kpad >> 5;
    const int sps = (nst + ksplit - 1) / ksplit;
    const int s0  = kz * sps;
    int s1 = s0 + sps; if (s1 > nst) s1 = nst;

    const int kc  = lane >> 4;
    const int fr  = lane & 15;
    const int wr  = (wid >> 1) * 64;
    const int wc  = (wid & 1) * 128;
    const int ksw = ((kc ^ ((fr >> 1) & 3)) << 3);

    if (s0 < s1) {
        const int n = s1 - s0;
        stage(0, s0);
        stage(1, s0 + ((n > 1) ? 1 : 0));
        for (int j = 0; j < n; j++) {
            asm volatile("s_waitcnt vmcnt(6)" ::: "memory");
            asm volatile("s_barrier" ::: "memory");
            {
                int jt = j + 2; if (jt > n - 1) jt = n - 1;
                stage((j + 2) % 3, s0 + jt);
            }
            const int buf = j % 3;
            half8 ah[4], wh[8];
            #pragma unroll
            for (int m = 0; m < 4; m++)
                ah[m] = *(const half8*)&smA[buf][wr + m * 16 + fr][ksw];
            #pragma unroll
            for (int nn = 0; nn < 8; nn++)
                wh[nn] = *(const half8*)&smW[buf][wc + nn * 16 + fr][ksw];
            #pragma unroll
            for (int m = 0; m < 4; m++)
                #pragma unroll
                for (int nn = 0; nn < 8; nn++)
                    acc1[m][nn] = __builtin_amdgcn_mfma_f32_16x16x32_f16(ah[m], wh[nn], acc1[m][nn], 0, 0, 0);
        }
        asm volatile("s_waitcnt vmcnt(0)" ::: "memory");
    }

    const int q4 = (lane >> 4) * 4;
    const size_t MN = (size_t)M * N;
    #pragma unroll
    for (int nn = 0; nn < 8; nn++) {
        const int gcol = bn + wc + nn * 16 + fr;
        const float bv = (OUT == 3) ? 0.0f : bias[gcol];
        #pragma unroll
        for (int m = 0; m < 4; m++) {
            #pragma unroll
            for (int j = 0; j < 4; j++) {
                const int grow = bm + wr + m * 16 + q4 + j;
                if (grow < M) {
                    float v = acc1[m][nn][j] + bv;
                    const size_t o = (size_t)grow * N + gcol;
                    if (OUT == 3)      Pf[(size_t)kz * MN + o] = v;
                    else if (OUT == 2) Cf[o] = v;
                    else               Chi[o] = (f16)fmaxf(v, 0.0f);
                }
            }
        }
    }
}

// ------- sum-of-slices + bias -> LayerNorm -> ReLU -> f16 store -------------
__global__ void ln_pf(
    const float* __restrict__ P, size_t MN, int ksplit,
    const float* __restrict__ bias, int dual,
    const float* __restrict__ gw, const float* __restrict__ bw,
    f16* __restrict__ oh, int Wd)
{
    const int row = blockIdx.x;
    const size_t base = (size_t)row * Wd;
    const int i8 = threadIdx.x * 8;
    const float* bp = bias + (dual ? ((row & 1) << 10) : 0);

    float v[8];
    {
        const float4 a0 = *(const float4*)(P + base + i8);
        const float4 a1 = *(const float4*)(P + base + i8 + 4);
        v[0]=a0.x; v[1]=a0.y; v[2]=a0.z; v[3]=a0.w;
        v[4]=a1.x; v[5]=a1.y; v[6]=a1.z; v[7]=a1.w;
    }
    for (int z = 1; z < ksplit; z++) {
        const float* Pz = P + (size_t)z * MN + base + i8;
        const float4 c0 = *(const float4*)(Pz);
        const float4 c1 = *(const float4*)(Pz + 4);
        v[0]+=c0.x; v[1]+=c0.y; v[2]+=c0.z; v[3]+=c0.w;
        v[4]+=c1.x; v[5]+=c1.y; v[6]+=c1.z; v[7]+=c1.w;
    }
    float s = 0.f, s2 = 0.f;
    #pragma unroll
    for (int k = 0; k < 8; k++) {
        v[k] += bp[i8 + k];
        s += v[k]; s2 += v[k] * v[k];
    }
    #pragma unroll
    for (int o = 1; o < 64; o <<= 1) { s += __shfl_xor(s, o); s2 += __shfl_xor(s2, o); }
    __shared__ float red[2][4];
    const int nw = blockDim.x >> 6;
    if ((threadIdx.x & 63) == 0) { red[0][threadIdx.x >> 6] = s; red[1][threadIdx.x >> 6] = s2; }
    __syncthreads();
    s = 0.f; s2 = 0.f;
    for (int w = 0; w < nw; w++) { s += red[0][w]; s2 += red[1][w]; }
    const float inv = 1.0f / (float)Wd;
    const float mean = s * inv;
    const float rstd = rsqrtf(s2 * inv - mean * mean + 1e-5f);
    const float4 g0 = *(const float4*)(gw + i8), g1 = *(const float4*)(gw + i8 + 4);
    const float4 b0 = *(const float4*)(bw + i8), b1 = *(const float4*)(bw + i8 + 4);
    const float gg[8] = {g0.x, g0.y, g0.z, g0.w, g1.x, g1.y, g1.z, g1.w};
    const float bb[8] = {b0.x, b0.y, b0.z, b0.w, b1.x, b1.y, b1.z, b1.w};
    half8 ho;
    #pragma unroll
    for (int k = 0; k < 8; k++)
        ho[k] = (f16)fmaxf((v[k] - mean) * rstd * gg[k] + bb[k], 0.0f);
    *(half8*)(oh + base + i8) = ho;
}

// ----- decode combine from f32 partial G (+bias) -> LN -> ReLU -> f16 -------
__global__ void comb_pf(
    const float* __restrict__ P, size_t MN, int ksplit,
    const float* __restrict__ bias,   // dec_b2 [2048]
    const float* __restrict__ gw, const float* __restrict__ bw,
    f16* __restrict__ oh, int Liv)
{
    const int row = blockIdx.x;
    const int Lp = Liv + 1;
    const int b = row / Lp, j = row - b * Lp;
    const int i8 = threadIdx.x * 8;

    auto sum8 = [&](size_t off, float* acc) {
        const float4 a0 = *(const float4*)(P + off);
        const float4 a1 = *(const float4*)(P + off + 4);
        acc[0]=a0.x; acc[1]=a0.y; acc[2]=a0.z; acc[3]=a0.w;
        acc[4]=a1.x; acc[5]=a1.y; acc[6]=a1.z; acc[7]=a1.w;
        for (int z = 1; z < ksplit; z++) {
            const float* Pz = P + (size_t)z * MN + off;
            const float4 c0 = *(const float4*)(Pz);
            const float4 c1 = *(const float4*)(Pz + 4);
            acc[0]+=c0.x; acc[1]+=c0.y; acc[2]+=c0.z; acc[3]+=c0.w;
            acc[4]+=c1.x; acc[5]+=c1.y; acc[6]+=c1.z; acc[7]+=c1.w;
        }
    };

    float v[8];
    if (j == 0) {
        sum8((size_t)(b * Liv) * 2048 + i8, v);
        #pragma unroll
        for (int k = 0; k < 8; k++) v[k] += bias[i8 + k];
    } else if (j == Liv) {
        sum8((size_t)(b * Liv + Liv - 1) * 2048 + 1024 + i8, v);
        #pragma unroll
        for (int k = 0; k < 8; k++) v[k] += bias[1024 + i8 + k];
    } else {
        float u[8];
        sum8((size_t)(b * Liv + j - 1) * 2048 + 1024 + i8, v);
        sum8((size_t)(b * Liv + j) * 2048 + i8, u);
        #pragma unroll
        for (int k = 0; k < 8; k++)
            v[k] = 0.5f * ((v[k] + bias[1024 + i8 + k]) + (u[k] + bias[i8 + k]));
    }
    float s = 0.f, s2 = 0.f;
    #pragma unroll
    for (int k = 0; k < 8; k++) { s += v[k]; s2 += v[k] * v[k]; }
    #pragma unroll
    for (int o = 1; o < 64; o <<= 1) { s += __shfl_xor(s, o); s2 += __shfl_xor(s2, o); }
    __shared__ float red[2][2];
    if ((threadIdx.x & 63) == 0) { red[0][threadIdx.x >> 6] = s; red[1][threadIdx.x >> 6] = s2; }
    __syncthreads();
    s = red[0][0] + red[0][1]; s2 = red[1][0] + red[1][1];
    const float mean = s * 9.765625e-4f;
    const float rstd = rsqrtf(s2 * 9.765625e-4f - mean * mean + 1e-5f);
    const float4 g0 = *(const float4*)(gw + i8), g1 = *(const float4*)(gw + i8 + 4);
    const float4 b0 = *(const float4*)(bw + i8), b1 = *(const float4*)(bw + i8 + 4);
    const float gg[8] = {g0.x, g0.y, g0.z, g0.w, g1.x, g1.y, g1.z, g1.w};
    const float bb[8] = {b0.x, b0.y, b0.z, b0.w, b1.x, b1.y, b1.z, b1.w};
    const size_t ob = (size_t)row * 1024 + i8;
    half8 ho;
    #pragma unroll
    for (int k = 0; k < 8; k++)
        ho[k] = (f16)fmaxf((v[k] - mean) * rstd * gg[k] + bb[k], 0.0f);
    *(half8*)(oh + ob) = ho;
}

// ---------------- weight transpose: W[K][N] -> Wt[N][K] f16 -----------------
__global__ __launch_bounds__(256) void wt_f16_k(
    const float* __restrict__ W, f16* __restrict__ Th, int K, int N)
{
    __shared__ float t[64][65];
    const int k0 = blockIdx.x * 64, n0 = blockIdx.y * 64;
    {
        const int j = threadIdx.x & 63, i0 = (threadIdx.x >> 6) * 16;
        for (int ii = 0; ii < 16; ii++) {
            int k = k0 + i0 + ii;
            t[i0 + ii][j] = (k < K) ? W[(size_t)k * N + n0 + j] : 0.f;
        }
    }
    __syncthreads();
    const int i = threadIdx.x & 63, j0 = (threadIdx.x >> 6) * 16;
    const int k = k0 + i;
    if (k < K) {
        for (int jj = 0; jj < 16; jj++)
            Th[(size_t)(n0 + j0 + jj) * K + k] = (f16)t[i][j0 + jj];
    }
}

// --------------------------- misc small kernels -----------------------------
__global__ void split_x_v(const float* __restrict__ x, f16* __restrict__ h, int n8) {
    int i = blockIdx.x * 256 + threadIdx.x;
    if (i >= n8) return;
    const int i8 = i * 8;
    const float4 f0 = *(const float4*)(x + i8), f1 = *(const float4*)(x + i8 + 4);
    const float vv[8] = {f0.x, f0.y, f0.z, f0.w, f1.x, f1.y, f1.z, f1.w};
    half8 ho;
    #pragma unroll
    for (int k = 0; k < 8; k++) ho[k] = (f16)vv[k];
    *(half8*)(h + i8) = ho;
}

__global__ void ts_init_k(f16* __restrict__ ts) {
    int e = blockIdx.x * 256 + threadIdx.x;
    if (e < 2048) {
        int rc = e >> 5, c = e & 31;
        float v = 0.f;
        if (rc >= 1) {
            int idx = (rc == 1) ? 1 : (rc == 2) ? 2 : (rc <= 4) ? 3 : ((rc + 10) / 3 - 1);
            if (c == 0) v = (float)rc;
            else if (c == idx) v = 1.f;
        }
        ts[e] = (f16)v;
    }
}

// ------------------------------ orchestration -------------------------------
extern "C" void kernel_launch(void* const* d_in, const int* in_sizes, int n_in,
                              void* d_out, int out_size, void* d_ws, size_t ws_size,
                              hipStream_t stream)
{
    const float* xin    = (const float*)d_in[0];
    const float* se_w1  = (const float*)d_in[1];
    const float* se_b1  = (const float*)d_in[2];
    const float* se_w2  = (const float*)d_in[3];
    const float* se_b2  = (const float*)d_in[4];
    const float* enc_w1 = (const float*)d_in[5];
    const float* enc_b1 = (const float*)d_in[6];
    const float* enc_g1 = (const float*)d_in[7];
    const float* enc_bb1= (const float*)d_in[8];
    const float* enc_w2 = (const float*)d_in[9];
    const float* enc_b2 = (const float*)d_in[10];
    const float* enc_g2 = (const float*)d_in[11];
    const float* enc_bb2= (const float*)d_in[12];
    const float* dec_w1 = (const float*)d_in[13];
    const float* dec_b1 = (const float*)d_in[14];
    const float* dec_g1 = (const float*)d_in[15];
    const float* dec_bb1= (const float*)d_in[16];
    const float* dec_w2 = (const float*)d_in[17];
    const float* dec_b2 = (const float*)d_in[18];
    const float* d2_g   = (const float*)d_in[19];
    const float* d2_b   = (const float*)d_in[20];
    const float* de_w1  = (const float*)d_in[21];
    const float* de_b1  = (const float*)d_in[22];
    const float* de_w2  = (const float*)d_in[23];
    const float* de_b2  = (const float*)d_in[24];

    // ------------- workspace layout (f16 units), tail-carved WR -------------
    const size_t ws_f16 = ws_size / 2;
    f16* ws = (f16*)d_ws;
    f16* Xh = ws;                                  // 4,194,304 (64*64*1024)
    f16* Hh = Xh + 4194304;                        // 6,193,152 (4032*1536)
    f16* WR = ws + (ws_f16 - 4757504);             // 4,755,456 + TS 2048
    f16* TS = WR + 4755456;
    float* PF = (float*)(Hh + 6193152);
    const long long pcap_ll = ((long long)ws_f16 - 4757504ll - 4194304ll - 6193152ll) / 2;
    const size_t pcap = (pcap_ll > 0) ? (size_t)pcap_ll : 0;
    const bool dec_unchunk = pcap >= 8257536ull;   // 4032x2048 f32 G-slice

    ts_init_k<<<8, 256, 0, stream>>>(TS);

    auto wt = [&](const float* W, int K, int N, f16* Th) {
        wt_f16_k<<<dim3((K + 63) / 64, N / 64), 256, 0, stream>>>(W, Th, K, N);
    };
    auto pick_ks = [&](int M, int N, int nst, size_t MN) {
        const int gx = ((N & 255) == 0) ? (N / 256) : (N / 128);
        const int gy = (M + 127) / 128;
        const int nat = gx * gy;
        int ks = (nat >= 448) ? 1 : (448 + nat - 1) / nat;
        if (ks > 8) ks = 8;
        if (ks > nst) ks = nst;
        while (ks > 1 && (size_t)ks * MN > pcap) ks--;
        return ks;
    };

    #define GEMM(MODE, OUT, Ah, lda, Wh, bias, Ch, Cf, Pfp, ks, M, N, K, Kpad, kb, Lo, Li, tsr) \
        do { \
            const int gy_ = ((M) + 127) / 128;                                     \
            if (((N) & 255) == 0) {                                                \
                const int nwg_ = ((N) / 256) * gy_ * (ks);                         \
                gemm_w2<MODE, OUT><<<nwg_, 256, 0, stream>>>(                      \
                    Ah, lda, Wh, bias, Ch, Cf, Pfp, (ks),                          \
                    M, N, K, Kpad, kb, Lo, Li, tsr, gy_, nwg_ >> 3, nwg_ & 7);     \
            } else {                                                               \
                const int nwg_ = ((N) / 128) * gy_ * (ks);                         \
                gemm_s1<MODE, OUT><<<nwg_, 256, 0, stream>>>(                      \
                    Ah, lda, Wh, bias, Ch, Cf, Pfp, (ks),                          \
                    M, N, K, Kpad, kb, Lo, Li, tsr, gy_, nwg_ >> 3, nwg_ & 7);     \
            }                                                                      \
        } while (0)

    // ---- scale_embedding (scratch inside PF region) ----
    {
        f16* W1h = WR;            f16* W2h = W1h + 163840;   // 655,360
        wt(se_w1, 256, 640, W1h);
        wt(se_w2, 640, 1024, W2h);
        f16* Sh  = (f16*)PF;               // 1,048,576
        f16* H1h = Sh + 1048576;           // 2,621,440 (4096x640)
        split_x_v<<<512, 256, 0, stream>>>(xin, Sh, 131072);
        GEMM(0, 1, Sh, 256, W1h, se_b1, H1h, (float*)0, (float*)0, 1,
             4096, 640, 256, 256, 256, 0, 0, TS);
        GEMM(0, 1, H1h, 640, W2h, se_b2, Xh, (float*)0, (float*)0, 1,
             4096, 1024, 640, 640, 640, 0, 0, TS);
    }

    // ---- encode ----
    {
        f16* E1h = WR;             f16* E2h = E1h + 3182592;  // 1,572,864
        wt(enc_w1, 2072, 1536, E1h);
        wt(enc_w2, 1536, 1024, E2h);
        for (int rc = 1; rc <= 63; rc++) {
            const int Lo = 64 - rc, Li = Lo + 1, Mc = 64 * Lo;
            const int k1 = pick_ks(Mc, 1536, 65, (size_t)Mc * 1536);
            GEMM(1, 3, Xh, 1024, E1h, enc_b1, (f16*)0, (float*)0,
                 PF, k1, Mc, 1536, 2072, 2080, 2048, Lo, Li, TS + rc * 32);
            ln_pf<<<Mc, 192, 0, stream>>>(PF, (size_t)Mc * 1536, k1, enc_b1, 0,
                                          enc_g1, enc_bb1, Hh, 1536);
            const int k2 = pick_ks(Mc, 1024, 48, (size_t)Mc * 1024);
            GEMM(0, 3, Hh, 1536, E2h, enc_b2, (f16*)0, (float*)0,
                 PF, k2, Mc, 1024, 1536, 1536, 1536, 0, 0, TS);
            ln_pf<<<Mc, 128, 0, stream>>>(PF, (size_t)Mc * 1024, k2, enc_b2, 0,
                                          enc_g2, enc_bb2, Xh, 1024);
        }
    }

    // ---- decode ----
    {
        f16* D1h = WR;             f16* D2h = D1h + 1609728;  // 3,145,728
        wt(dec_w1, 1048, 1536, D1h);
        wt(dec_w2, 1536, 2048, D2h);

        // first step: [64,1024] -> [64,2048] -> LN over [128,1024] view
        {
            const int k1 = pick_ks(64, 1536, 33, (size_t)64 * 1536);
            GEMM(2, 3, Xh, 1024, D1h, dec_b1, (f16*)0, (float*)0,
                 PF, k1, 64, 1536, 1048, 1056, 1024, 0, 0, TS + 63 * 32);
            ln_pf<<<64, 192, 0, stream>>>(PF, (size_t)64 * 1536, k1, dec_b1, 0,
                                          dec_g1, dec_bb1, Hh, 1536);
            const int k2 = pick_ks(64, 2048, 48, (size_t)64 * 2048);
            GEMM(0, 3, Hh, 1536, D2h, dec_b2, (f16*)0, (float*)0,
                 PF, k2, 64, 2048, 1536, 1536, 1536, 0, 0, TS);
            // 64x2048 flat == 128x1024 flat; dual-bias by row parity
            ln_pf<<<128, 128, 0, stream>>>(PF, (size_t)64 * 2048, k2, dec_b2, 1,
                                           d2_g, d2_b, Xh, 1024);
        }

        for (int rc = 62; rc >= 1; rc--) {
            const int Li = 64 - rc;
            const int nch = (!dec_unchunk && 64 * Li > 2016) ? 2 : 1, nb = 64 / nch;
            for (int c = nch - 1; c >= 0; c--) {        // high batches first
                const int b0 = c * nb, Mc = nb * Li;
                const size_t ai = (size_t)b0 * Li * 1024;
                const size_t oi = (size_t)b0 * (Li + 1) * 1024;
                const int k1 = pick_ks(Mc, 1536, 33, (size_t)Mc * 1536);
                GEMM(2, 3, Xh + ai, 1024, D1h, dec_b1, (f16*)0, (float*)0,
                     PF, k1, Mc, 1536, 1048, 1056, 1024, 0, 0, TS + rc * 32);
                ln_pf<<<Mc, 192, 0, stream>>>(PF, (size_t)Mc * 1536, k1, dec_b1, 0,
                                              dec_g1, dec_bb1, Hh, 1536);
                const int k2 = pick_ks(Mc, 2048, 48, (size_t)Mc * 2048);
                GEMM(0, 3, Hh, 1536, D2h, dec_b2, (f16*)0, (float*)0,
                     PF, k2, Mc, 2048, 1536, 1536, 1536, 0, 0, TS);
                comb_pf<<<nb * (Li + 1), 128, 0, stream>>>(
                    PF, (size_t)Mc * 2048, k2, dec_b2, d2_g, d2_b,
                    Xh + oi, Li);
            }
        }
    }

    // ---- descale_embedding ----
    {
        f16* W1h = WR;            f16* W2h = W1h + 655360;   // 163,840
        wt(de_w1, 1024, 640, W1h);
        wt(de_w2, 640, 256, W2h);
        f16* H1h = (f16*)PF;               // 2,621,440 (4096x640)
        GEMM(0, 1, Xh, 1024, W1h, de_b1, H1h, (float*)0, (float*)0, 1,
             4096, 640, 1024, 1024, 1024, 0, 0, TS);
        GEMM(0, 2, H1h, 640, W2h, de_b2, (f16*)0, (float*)d_out, (float*)0, 1,
             4096, 256, 640, 640, 640, 0, 0, TS);
    }
    #undef GEMM
}

// Round 17
// 7845.984 us; speedup vs baseline: 1.3167x; 1.3167x over previous
//
#include <hip/hip_runtime.h>

// ---------------------------------------------------------------------------
// RAE forward, single-product f16 MFMA GEMMs + deterministic split-K.
// Weights AND activations: single f16 (R15).  C = A@W, f32 accumulate.
// GEMM: 128x128 tile, 4 waves, A+W via global_load_lds (contiguous-line
// staging R13, sigma(r)=(r>>1)&3 swizzle R14), 3-buffer LDS + counted
// s_waitcnt vmcnt(4) 2-deep pipeline (R12), 48KB LDS, split-K into
// P[kz][M][N] f32 summed in LN pass. Best measured: 7.85 ms (R15).
//
// FAILED-EXPERIMENT LEDGER (do not repeat):
//  - A streamed global->VGPR (R5: -27%, R7: -330%)
//  - split-K target 512 / cap 16 (R8: +4% slower) — keep 448 / cap 8
//  - wide 128x256 tiles: 8-wave 96KB (R9: +12%), 4-wave 72KB (R16: +31%)
//    — grid shrink + heavier per-barrier step always loses; keep 128x128
//  - counted-vmcnt alone (R12: +2%); bank-swizzle fix alone (R14: +1.8%)
// Composed floor: ~25GB staging @ ~5TB/s + LN traffic + ~500-launch serial
// chain ~= 7.8 ms ~= measured. At the decomposition's memory+launch floor.
// ---------------------------------------------------------------------------

typedef _Float16 f16;
typedef _Float16 half8 __attribute__((ext_vector_type(8)));
typedef float floatx4 __attribute__((ext_vector_type(4)));

__device__ __forceinline__ void gld_lds16(const f16* g, f16* l) {
    __builtin_amdgcn_global_load_lds(
        (const __attribute__((address_space(1))) void*)g,
        (__attribute__((address_space(3))) void*)l, 16, 0, 0);
}

// ----------------------------- GEMM ----------------------------------------
// MODE 0: plain A. MODE 1: enc-cat (row b*Li+l; k>=kbound -> ts table).
// MODE 2: dec-cat (k>=kbound -> ts table).
// OUT 1: bias+relu+f16 store; OUT 2: bias+fp32 store; OUT 3: f32 partial
// slice store (no bias).
template<int MODE, int OUT>
__global__ __launch_bounds__(256, 2) void gemm_s1(
    const f16* __restrict__ Ahi, int lda,
    const f16* __restrict__ Whi,                     // [N][K] transposed, f16
    const float* __restrict__ bias,
    f16* __restrict__ Chi, float* __restrict__ Cf,
    float* __restrict__ Pf, int ksplit,
    int M, int N, int K, int Kpad, int kbound, int Lo, int Li,
    const f16* __restrict__ tsrow,
    int gy, int q, int r)
{
    // [buf 0..2][arr: A,W][row/col 0..127][32 k]  -> 48 KiB
    __shared__ __align__(16) f16 sm[3][2][128][32];

    const int tid  = threadIdx.x;
    const int lane = tid & 63;
    const int wid  = tid >> 6;

    // bijective XCD swizzle (m204); rank = (bx*gy + by)*ksplit + kz
    const int bid = blockIdx.x;
    const int xcd = bid & 7, jj = bid >> 3;
    const int rank = (xcd < r) ? xcd * (q + 1) + jj
                               : r * (q + 1) + (xcd - r) * q + jj;
    const int t  = rank / ksplit;
    const int kz = rank - t * ksplit;
    const int bx = t / gy, by = t - bx * gy;
    const int bm = by * 128;
    const int bn = bx * 128;

    // staging: wave wid covers rows/cols [wid*32, wid*32+32); lane = rl*4+kp
    // loads the row's 16B at k-part (kp ^ ((rl>>1)&3)) -> 4 consecutive lanes
    // = 64B contiguous; read side 2-way bank (free).
    const int rl   = lane >> 2;
    const int kp   = lane & 3;
    const int kofs = ((kp ^ ((rl >> 1) & 3)) << 3);  // f16 offset within row

    const f16* aph[2];
    const f16* wph[2];
    #pragma unroll
    for (int it = 0; it < 2; it++) {
        const int trow = wid * 32 + it * 16 + rl;    // tile-local 0..127
        int gr = bm + trow; if (gr > M - 1) gr = M - 1;
        int arow;
        if (MODE == 1) { int b = gr / Lo; int l = gr - b * Lo; arow = b * Li + l; }
        else arow = gr;
        aph[it] = Ahi + (size_t)arow * lda;
        const int col = bn + trow;                   // N % 128 == 0 -> in range
        wph[it] = Whi + (size_t)col * K;
    }

    // exactly 4 global_load_lds per wave per stage (vmcnt cadence relies on it)
    auto stage = [&](int buf, int sstep) {
        const int k0 = sstep << 5;
        #pragma unroll
        for (int it = 0; it < 2; it++) {
            const int lbase = wid * 32 + it * 16;
            const f16* sh;
            if (MODE == 0 || k0 < kbound) sh = aph[it] + (k0 + kofs);
            else                          sh = tsrow + (k0 - kbound) + kofs;
            gld_lds16(sh, &sm[buf][0][lbase][0] + (size_t)lane * 8);
            int kw = k0 + kofs; if (kw > K - 8) kw = K - 8;   // dup tail; A=0 there
            gld_lds16(wph[it] + kw, &sm[buf][1][lbase][0] + (size_t)lane * 8);
        }
    };

    floatx4 acc1[4][4] = {};

    const int nst = Kpad >> 5;
    const int sps = (nst + ksplit - 1) / ksplit;
    const int s0  = kz * sps;
    int s1 = s0 + sps; if (s1 > nst) s1 = nst;

    const int kc  = lane >> 4;
    const int fr  = lane & 15;
    const int wr  = (wid >> 1) * 64;
    const int wc  = (wid & 1) * 64;
    const int ksw = ((kc ^ ((fr >> 1) & 3)) << 3);   // read-side swizzled slot

    if (s0 < s1) {
        const int n = s1 - s0;
        stage(0, s0);
        stage(1, s0 + ((n > 1) ? 1 : 0));
        for (int j = 0; j < n; j++) {
            asm volatile("s_waitcnt vmcnt(4)" ::: "memory");
            asm volatile("s_barrier" ::: "memory");
            {
                int jt = j + 2; if (jt > n - 1) jt = n - 1;
                stage((j + 2) % 3, s0 + jt);
            }
            const int buf = j % 3;
            half8 ah[4], wh[4];
            #pragma unroll
            for (int m = 0; m < 4; m++)
                ah[m] = *(const half8*)&sm[buf][0][wr + m * 16 + fr][ksw];
            #pragma unroll
            for (int nn = 0; nn < 4; nn++)
                wh[nn] = *(const half8*)&sm[buf][1][wc + nn * 16 + fr][ksw];
            #pragma unroll
            for (int m = 0; m < 4; m++)
                #pragma unroll
                for (int nn = 0; nn < 4; nn++)
                    acc1[m][nn] = __builtin_amdgcn_mfma_f32_16x16x32_f16(ah[m], wh[nn], acc1[m][nn], 0, 0, 0);
        }
        asm volatile("s_waitcnt vmcnt(0)" ::: "memory");
    }

    // epilogue: C/D frag layout col = lane&15, row = (lane>>4)*4 + j
    const int q4 = (lane >> 4) * 4;
    const size_t MN = (size_t)M * N;
    #pragma unroll
    for (int nn = 0; nn < 4; nn++) {
        const int gcol = bn + wc + nn * 16 + fr;
        const float bv = (OUT == 3) ? 0.0f : bias[gcol];
        #pragma unroll
        for (int m = 0; m < 4; m++) {
            #pragma unroll
            for (int j = 0; j < 4; j++) {
                const int grow = bm + wr + m * 16 + q4 + j;
                if (grow < M) {
                    float v = acc1[m][nn][j] + bv;
                    const size_t o = (size_t)grow * N + gcol;
                    if (OUT == 3) {
                        Pf[(size_t)kz * MN + o] = v;
                    } else if (OUT == 2) {
                        Cf[o] = v;
                    } else {
                        Chi[o] = (f16)fmaxf(v, 0.0f);
                    }
                }
            }
        }
    }
}

// ------- sum-of-slices + bias -> LayerNorm -> ReLU -> f16 store -------------
// block = Wd/8 threads (128 or 192). dual: bias += (row&1)*1024 (dec reshape).
__global__ void ln_pf(
    const float* __restrict__ P, size_t MN, int ksplit,
    const float* __restrict__ bias, int dual,
    const float* __restrict__ gw, const float* __restrict__ bw,
    f16* __restrict__ oh, int Wd)
{
    const int row = blockIdx.x;
    const size_t base = (size_t)row * Wd;
    const int i8 = threadIdx.x * 8;
    const float* bp = bias + (dual ? ((row & 1) << 10) : 0);

    float v[8];
    {
        const float4 a0 = *(const float4*)(P + base + i8);
        const float4 a1 = *(const float4*)(P + base + i8 + 4);
        v[0]=a0.x; v[1]=a0.y; v[2]=a0.z; v[3]=a0.w;
        v[4]=a1.x; v[5]=a1.y; v[6]=a1.z; v[7]=a1.w;
    }
    for (int z = 1; z < ksplit; z++) {
        const float* Pz = P + (size_t)z * MN + base + i8;
        const float4 c0 = *(const float4*)(Pz);
        const float4 c1 = *(const float4*)(Pz + 4);
        v[0]+=c0.x; v[1]+=c0.y; v[2]+=c0.z; v[3]+=c0.w;
        v[4]+=c1.x; v[5]+=c1.y; v[6]+=c1.z; v[7]+=c1.w;
    }
    float s = 0.f, s2 = 0.f;
    #pragma unroll
    for (int k = 0; k < 8; k++) {
        v[k] += bp[i8 + k];
        s += v[k]; s2 += v[k] * v[k];
    }
    #pragma unroll
    for (int o = 1; o < 64; o <<= 1) { s += __shfl_xor(s, o); s2 += __shfl_xor(s2, o); }
    __shared__ float red[2][4];
    const int nw = blockDim.x >> 6;
    if ((threadIdx.x & 63) == 0) { red[0][threadIdx.x >> 6] = s; red[1][threadIdx.x >> 6] = s2; }
    __syncthreads();
    s = 0.f; s2 = 0.f;
    for (int w = 0; w < nw; w++) { s += red[0][w]; s2 += red[1][w]; }
    const float inv = 1.0f / (float)Wd;
    const float mean = s * inv;
    const float rstd = rsqrtf(s2 * inv - mean * mean + 1e-5f);
    const float4 g0 = *(const float4*)(gw + i8), g1 = *(const float4*)(gw + i8 + 4);
    const float4 b0 = *(const float4*)(bw + i8), b1 = *(const float4*)(bw + i8 + 4);
    const float gg[8] = {g0.x, g0.y, g0.z, g0.w, g1.x, g1.y, g1.z, g1.w};
    const float bb[8] = {b0.x, b0.y, b0.z, b0.w, b1.x, b1.y, b1.z, b1.w};
    half8 ho;
    #pragma unroll
    for (int k = 0; k < 8; k++)
        ho[k] = (f16)fmaxf((v[k] - mean) * rstd * gg[k] + bb[k], 0.0f);
    *(half8*)(oh + base + i8) = ho;
}

// ----- decode combine from f32 partial G (+bias) -> LN -> ReLU -> f16 -------
// P slices hold G[Mc=nb*Liv rows][2048]; output rows nb*(Liv+1) x 1024.
__global__ void comb_pf(
    const float* __restrict__ P, size_t MN, int ksplit,
    const float* __restrict__ bias,   // dec_b2 [2048]
    const float* __restrict__ gw, const float* __restrict__ bw,
    f16* __restrict__ oh, int Liv)
{
    const int row = blockIdx.x;
    const int Lp = Liv + 1;
    const int b = row / Lp, j = row - b * Lp;
    const int i8 = threadIdx.x * 8;

    auto sum8 = [&](size_t off, float* acc) {
        const float4 a0 = *(const float4*)(P + off);
        const float4 a1 = *(const float4*)(P + off + 4);
        acc[0]=a0.x; acc[1]=a0.y; acc[2]=a0.z; acc[3]=a0.w;
        acc[4]=a1.x; acc[5]=a1.y; acc[6]=a1.z; acc[7]=a1.w;
        for (int z = 1; z < ksplit; z++) {
            const float* Pz = P + (size_t)z * MN + off;
            const float4 c0 = *(const float4*)(Pz);
            const float4 c1 = *(const float4*)(Pz + 4);
            acc[0]+=c0.x; acc[1]+=c0.y; acc[2]+=c0.z; acc[3]+=c0.w;
            acc[4]+=c1.x; acc[5]+=c1.y; acc[6]+=c1.z; acc[7]+=c1.w;
        }
    };

    float v[8];
    if (j == 0) {
        sum8((size_t)(b * Liv) * 2048 + i8, v);
        #pragma unroll
        for (int k = 0; k < 8; k++) v[k] += bias[i8 + k];
    } else if (j == Liv) {
        sum8((size_t)(b * Liv + Liv - 1) * 2048 + 1024 + i8, v);
        #pragma unroll
        for (int k = 0; k < 8; k++) v[k] += bias[1024 + i8 + k];
    } else {
        float u[8];
        sum8((size_t)(b * Liv + j - 1) * 2048 + 1024 + i8, v);
        sum8((size_t)(b * Liv + j) * 2048 + i8, u);
        #pragma unroll
        for (int k = 0; k < 8; k++)
            v[k] = 0.5f * ((v[k] + bias[1024 + i8 + k]) + (u[k] + bias[i8 + k]));
    }
    float s = 0.f, s2 = 0.f;
    #pragma unroll
    for (int k = 0; k < 8; k++) { s += v[k]; s2 += v[k] * v[k]; }
    #pragma unroll
    for (int o = 1; o < 64; o <<= 1) { s += __shfl_xor(s, o); s2 += __shfl_xor(s2, o); }
    __shared__ float red[2][2];
    if ((threadIdx.x & 63) == 0) { red[0][threadIdx.x >> 6] = s; red[1][threadIdx.x >> 6] = s2; }
    __syncthreads();
    s = red[0][0] + red[0][1]; s2 = red[1][0] + red[1][1];
    const float mean = s * 9.765625e-4f;
    const float rstd = rsqrtf(s2 * 9.765625e-4f - mean * mean + 1e-5f);
    const float4 g0 = *(const float4*)(gw + i8), g1 = *(const float4*)(gw + i8 + 4);
    const float4 b0 = *(const float4*)(bw + i8), b1 = *(const float4*)(bw + i8 + 4);
    const float gg[8] = {g0.x, g0.y, g0.z, g0.w, g1.x, g1.y, g1.z, g1.w};
    const float bb[8] = {b0.x, b0.y, b0.z, b0.w, b1.x, b1.y, b1.z, b1.w};
    const size_t ob = (size_t)row * 1024 + i8;
    half8 ho;
    #pragma unroll
    for (int k = 0; k < 8; k++)
        ho[k] = (f16)fmaxf((v[k] - mean) * rstd * gg[k] + bb[k], 0.0f);
    *(half8*)(oh + ob) = ho;
}

// ---------------- weight transpose: W[K][N] -> Wt[N][K] f16 -----------------
__global__ __launch_bounds__(256) void wt_f16_k(
    const float* __restrict__ W, f16* __restrict__ Th, int K, int N)
{
    __shared__ float t[64][65];
    const int k0 = blockIdx.x * 64, n0 = blockIdx.y * 64;
    {
        const int j = threadIdx.x & 63, i0 = (threadIdx.x >> 6) * 16;
        for (int ii = 0; ii < 16; ii++) {
            int k = k0 + i0 + ii;
            t[i0 + ii][j] = (k < K) ? W[(size_t)k * N + n0 + j] : 0.f;
        }
    }
    __syncthreads();
    const int i = threadIdx.x & 63, j0 = (threadIdx.x >> 6) * 16;
    const int k = k0 + i;
    if (k < K) {
        for (int jj = 0; jj < 16; jj++)
            Th[(size_t)(n0 + j0 + jj) * K + k] = (f16)t[i][j0 + jj];
    }
}

// --------------------------- misc small kernels -----------------------------
__global__ void split_x_v(const float* __restrict__ x, f16* __restrict__ h, int n8) {
    int i = blockIdx.x * 256 + threadIdx.x;
    if (i >= n8) return;
    const int i8 = i * 8;
    const float4 f0 = *(const float4*)(x + i8), f1 = *(const float4*)(x + i8 + 4);
    const float vv[8] = {f0.x, f0.y, f0.z, f0.w, f1.x, f1.y, f1.z, f1.w};
    half8 ho;
    #pragma unroll
    for (int k = 0; k < 8; k++) ho[k] = (f16)vv[k];
    *(half8*)(h + i8) = ho;
}

__global__ void ts_init_k(f16* __restrict__ ts) {
    int e = blockIdx.x * 256 + threadIdx.x;
    if (e < 2048) {
        int rc = e >> 5, c = e & 31;
        float v = 0.f;
        if (rc >= 1) {
            int idx = (rc == 1) ? 1 : (rc == 2) ? 2 : (rc <= 4) ? 3 : ((rc + 10) / 3 - 1);
            if (c == 0) v = (float)rc;
            else if (c == idx) v = 1.f;
        }
        ts[e] = (f16)v;
    }
}

// ------------------------------ orchestration -------------------------------
extern "C" void kernel_launch(void* const* d_in, const int* in_sizes, int n_in,
                              void* d_out, int out_size, void* d_ws, size_t ws_size,
                              hipStream_t stream)
{
    const float* xin    = (const float*)d_in[0];
    const float* se_w1  = (const float*)d_in[1];
    const float* se_b1  = (const float*)d_in[2];
    const float* se_w2  = (const float*)d_in[3];
    const float* se_b2  = (const float*)d_in[4];
    const float* enc_w1 = (const float*)d_in[5];
    const float* enc_b1 = (const float*)d_in[6];
    const float* enc_g1 = (const float*)d_in[7];
    const float* enc_bb1= (const float*)d_in[8];
    const float* enc_w2 = (const float*)d_in[9];
    const float* enc_b2 = (const float*)d_in[10];
    const float* enc_g2 = (const float*)d_in[11];
    const float* enc_bb2= (const float*)d_in[12];
    const float* dec_w1 = (const float*)d_in[13];
    const float* dec_b1 = (const float*)d_in[14];
    const float* dec_g1 = (const float*)d_in[15];
    const float* dec_bb1= (const float*)d_in[16];
    const float* dec_w2 = (const float*)d_in[17];
    const float* dec_b2 = (const float*)d_in[18];
    const float* d2_g   = (const float*)d_in[19];
    const float* d2_b   = (const float*)d_in[20];
    const float* de_w1  = (const float*)d_in[21];
    const float* de_b1  = (const float*)d_in[22];
    const float* de_w2  = (const float*)d_in[23];
    const float* de_b2  = (const float*)d_in[24];

    // ------------- workspace layout (f16 units), tail-carved WR -------------
    const size_t ws_f16 = ws_size / 2;
    f16* ws = (f16*)d_ws;
    f16* Xh = ws;                                  // 4,194,304 (64*64*1024)
    f16* Hh = Xh + 4194304;                        // 6,193,152 (4032*1536)
    f16* WR = ws + (ws_f16 - 4757504);             // 4,755,456 + TS 2048
    f16* TS = WR + 4755456;
    float* PF = (float*)(Hh + 6193152);
    const long long pcap_ll = ((long long)ws_f16 - 4757504ll - 4194304ll - 6193152ll) / 2;
    const size_t pcap = (pcap_ll > 0) ? (size_t)pcap_ll : 0;
    const bool dec_unchunk = pcap >= 8257536ull;   // 4032x2048 f32 G-slice

    ts_init_k<<<8, 256, 0, stream>>>(TS);

    auto wt = [&](const float* W, int K, int N, f16* Th) {
        wt_f16_k<<<dim3((K + 63) / 64, N / 64), 256, 0, stream>>>(W, Th, K, N);
    };
    auto pick_ks = [&](int natural, int nst, size_t MN) {
        int ks = (natural >= 448) ? 1 : (448 + natural - 1) / natural;
        if (ks > 8) ks = 8;
        if (ks > nst) ks = nst;
        while (ks > 1 && (size_t)ks * MN > pcap) ks--;
        return ks;
    };

    #define GEMM(MODE, OUT, Ah, lda, Wh, bias, Ch, Cf, Pfp, ks, M, N, K, Kpad, kb, Lo, Li, tsr) \
        do { \
            const int gx_ = (N) / 128, gy_ = ((M) + 127) / 128;                \
            const int nwg_ = gx_ * gy_ * (ks);                                 \
            gemm_s1<MODE, OUT><<<nwg_, 256, 0, stream>>>(                      \
                Ah, lda, Wh, bias, Ch, Cf, Pfp, (ks),                          \
                M, N, K, Kpad, kb, Lo, Li, tsr, gy_, nwg_ >> 3, nwg_ & 7);     \
        } while (0)

    // ---- scale_embedding (scratch inside PF region) ----
    {
        f16* W1h = WR;            f16* W2h = W1h + 163840;   // 655,360
        wt(se_w1, 256, 640, W1h);
        wt(se_w2, 640, 1024, W2h);
        f16* Sh  = (f16*)PF;               // 1,048,576
        f16* H1h = Sh + 1048576;           // 2,621,440 (4096x640)
        split_x_v<<<512, 256, 0, stream>>>(xin, Sh, 131072);
        GEMM(0, 1, Sh, 256, W1h, se_b1, H1h, (float*)0, (float*)0, 1,
             4096, 640, 256, 256, 256, 0, 0, TS);
        GEMM(0, 1, H1h, 640, W2h, se_b2, Xh, (float*)0, (float*)0, 1,
             4096, 1024, 640, 640, 640, 0, 0, TS);
    }

    // ---- encode ----
    {
        f16* E1h = WR;             f16* E2h = E1h + 3182592;  // 1,572,864
        wt(enc_w1, 2072, 1536, E1h);
        wt(enc_w2, 1536, 1024, E2h);
        for (int rc = 1; rc <= 63; rc++) {
            const int Lo = 64 - rc, Li = Lo + 1, Mc = 64 * Lo;
            const int gy = (Mc + 127) / 128;
            const int k1 = pick_ks(12 * gy, 65, (size_t)Mc * 1536);
            GEMM(1, 3, Xh, 1024, E1h, enc_b1, (f16*)0, (float*)0,
                 PF, k1, Mc, 1536, 2072, 2080, 2048, Lo, Li, TS + rc * 32);
            ln_pf<<<Mc, 192, 0, stream>>>(PF, (size_t)Mc * 1536, k1, enc_b1, 0,
                                          enc_g1, enc_bb1, Hh, 1536);
            const int k2 = pick_ks(8 * gy, 48, (size_t)Mc * 1024);
            GEMM(0, 3, Hh, 1536, E2h, enc_b2, (f16*)0, (float*)0,
                 PF, k2, Mc, 1024, 1536, 1536, 1536, 0, 0, TS);
            ln_pf<<<Mc, 128, 0, stream>>>(PF, (size_t)Mc * 1024, k2, enc_b2, 0,
                                          enc_g2, enc_bb2, Xh, 1024);
        }
    }

    // ---- decode ----
    {
        f16* D1h = WR;             f16* D2h = D1h + 1609728;  // 3,145,728
        wt(dec_w1, 1048, 1536, D1h);
        wt(dec_w2, 1536, 2048, D2h);

        // first step: [64,1024] -> [64,2048] -> LN over [128,1024] view
        {
            const int k1 = pick_ks(12, 33, (size_t)64 * 1536);
            GEMM(2, 3, Xh, 1024, D1h, dec_b1, (f16*)0, (float*)0,
                 PF, k1, 64, 1536, 1048, 1056, 1024, 0, 0, TS + 63 * 32);
            ln_pf<<<64, 192, 0, stream>>>(PF, (size_t)64 * 1536, k1, dec_b1, 0,
                                          dec_g1, dec_bb1, Hh, 1536);
            const int k2 = pick_ks(16, 48, (size_t)64 * 2048);
            GEMM(0, 3, Hh, 1536, D2h, dec_b2, (f16*)0, (float*)0,
                 PF, k2, 64, 2048, 1536, 1536, 1536, 0, 0, TS);
            // 64x2048 flat == 128x1024 flat; dual-bias by row parity
            ln_pf<<<128, 128, 0, stream>>>(PF, (size_t)64 * 2048, k2, dec_b2, 1,
                                           d2_g, d2_b, Xh, 1024);
        }

        for (int rc = 62; rc >= 1; rc--) {
            const int Li = 64 - rc;
            const int nch = (!dec_unchunk && 64 * Li > 2016) ? 2 : 1, nb = 64 / nch;
            for (int c = nch - 1; c >= 0; c--) {        // high batches first
                const int b0 = c * nb, Mc = nb * Li;
                const size_t ai = (size_t)b0 * Li * 1024;
                const size_t oi = (size_t)b0 * (Li + 1) * 1024;
                const int gy = (Mc + 127) / 128;
                const int k1 = pick_ks(12 * gy, 33, (size_t)Mc * 1536);
                GEMM(2, 3, Xh + ai, 1024, D1h, dec_b1, (f16*)0, (float*)0,
                     PF, k1, Mc, 1536, 1048, 1056, 1024, 0, 0, TS + rc * 32);
                ln_pf<<<Mc, 192, 0, stream>>>(PF, (size_t)Mc * 1536, k1, dec_b1, 0,
                                              dec_g1, dec_bb1, Hh, 1536);
                const int k2 = pick_ks(16 * gy, 48, (size_t)Mc * 2048);
                GEMM(0, 3, Hh, 1536, D2h, dec_b2, (f16*)0, (float*)0,
                     PF, k2, Mc, 2048, 1536, 1536, 1536, 0, 0, TS);
                comb_pf<<<nb * (Li + 1), 128, 0, stream>>>(
                    PF, (size_t)Mc * 2048, k2, dec_b2, d2_g, d2_b,
                    Xh + oi, Li);
            }
        }
    }

    // ---- descale_embedding ----
    {
        f16* W1h = WR;            f16* W2h = W1h + 655360;   // 163,840
        wt(de_w1, 1024, 640, W1h);
        wt(de_w2, 640, 256, W2h);
        f16* H1h = (f16*)PF;               // 2,621,440 (4096x640)
        GEMM(0, 1, Xh, 1024, W1h, de_b1, H1h, (float*)0, (float*)0, 1,
             4096, 640, 1024, 1024, 1024, 0, 0, TS);
        GEMM(0, 2, H1h, 640, W2h, de_b2, (f16*)0, (float*)d_out, (float*)0, 1,
             4096, 256, 640, 640, 640, 0, 0, TS);
    }
    #undef GEMM
}